// Round 1
// baseline (2850.801 us; speedup 1.0000x reference)
//
#include <hip/hip_runtime.h>
#include <hip/hip_bf16.h>
#include <cstdint>

typedef __hip_bfloat16 bf16;
typedef __attribute__((ext_vector_type(8))) short short8;   // 8 bf16 = 4 VGPRs
typedef __attribute__((ext_vector_type(4))) float f32x4;

__device__ __forceinline__ f32x4 mfma16(short8 a, short8 b, f32x4 c) {
  return __builtin_amdgcn_mfma_f32_16x16x32_bf16(a, b, c, 0, 0, 0);
}

// ---------------- elementwise / conversion ----------------

__global__ void __launch_bounds__(256) cvt_f32_bf16(const float* __restrict__ in,
                                                    bf16* __restrict__ out, int n) {
  int i = blockIdx.x * 256 + threadIdx.x;
  if (i < n) out[i] = __float2bfloat16(in[i]);
}

__global__ void __launch_bounds__(256) bcast_latents(const float* __restrict__ lin,
                                                     float* __restrict__ lat) {
  int i = blockIdx.x * 256 + threadIdx.x;
  lat[i] = lin[i & 65535];   // latents is (64,1024) broadcast over 32 batches
}

// src: K x N f32  ->  dst: N x K bf16 (transposed, for GEMM B^T input)
__global__ void __launch_bounds__(256) transpose_cvt(const float* __restrict__ src,
                                                     bf16* __restrict__ dst,
                                                     int K, int N) {
  __shared__ float tile[32][33];
  int n0 = blockIdx.x * 32, k0 = blockIdx.y * 32;
  int tx = threadIdx.x & 31, ty = threadIdx.x >> 5;
#pragma unroll
  for (int j = 0; j < 32; j += 8)
    tile[ty + j][tx] = src[(size_t)(k0 + ty + j) * N + n0 + tx];
  __syncthreads();
#pragma unroll
  for (int j = 0; j < 32; j += 8)
    dst[(size_t)(n0 + ty + j) * K + k0 + tx] = __float2bfloat16(tile[tx][ty + j]);
}

// ---------------- layernorm family (cols fixed at 1024) ----------------

__device__ __forceinline__ void row_stats(const float* x, int tid, float v[4],
                                          float& mean, float& rstd, float* red) {
  float s = 0.f, s2 = 0.f;
#pragma unroll
  for (int j = 0; j < 4; j++) {
    v[j] = x[tid + j * 256];
    s += v[j]; s2 += v[j] * v[j];
  }
#pragma unroll
  for (int o = 32; o > 0; o >>= 1) {
    s += __shfl_down(s, o);
    s2 += __shfl_down(s2, o);
  }
  int w = tid >> 6;
  if ((tid & 63) == 0) { red[w] = s; red[4 + w] = s2; }
  __syncthreads();
  s = red[0] + red[1] + red[2] + red[3];
  s2 = red[4] + red[5] + red[6] + red[7];
  mean = s * (1.f / 1024.f);
  float var = s2 * (1.f / 1024.f) - mean * mean;
  rstd = rsqrtf(var + 1e-5f);
}

// out2 (nullable): duplicate write into concat buffer rows (b*336 + 257 + q)
__global__ void __launch_bounds__(256) ln_to_bf16(const float* __restrict__ in,
                                                  const float* __restrict__ g,
                                                  const float* __restrict__ bb,
                                                  bf16* __restrict__ out,
                                                  bf16* __restrict__ out2) {
  __shared__ float red[8];
  int row = blockIdx.x, tid = threadIdx.x;
  const float* x = in + (size_t)row * 1024;
  float v[4], mean, rstd;
  row_stats(x, tid, v, mean, rstd, red);
  bf16* o1 = out + (size_t)row * 1024;
  bf16* o2 = out2 ? out2 + ((size_t)(row >> 6) * 336 + 257 + (row & 63)) * 1024 : nullptr;
#pragma unroll
  for (int j = 0; j < 4; j++) {
    int c = tid + j * 256;
    float y = (v[j] - mean) * rstd;
    if (g) y = y * g[c] + bb[c];
    bf16 hh = __float2bfloat16(y);
    o1[c] = hh;
    if (o2) o2[c] = hh;
  }
}

__global__ void __launch_bounds__(256) ln_to_f32(const float* __restrict__ in,
                                                 const float* __restrict__ g,
                                                 const float* __restrict__ bb,
                                                 float* __restrict__ out) {
  __shared__ float red[8];
  int row = blockIdx.x, tid = threadIdx.x;
  const float* x = in + (size_t)row * 1024;
  float v[4], mean, rstd;
  row_stats(x, tid, v, mean, rstd, red);
  float* o1 = out + (size_t)row * 1024;
#pragma unroll
  for (int j = 0; j < 4; j++) {
    int c = tid + j * 256;
    o1[c] = (v[j] - mean) * rstd * g[c] + bb[c];
  }
}

// cat rows: per batch 336 rows = [xn(257) | ln_lat(64) | zero pad(15)]
// this kernel fills xn rows (affine on precomputed xhat) and the zero pad.
__global__ void __launch_bounds__(256) affine_cat(const bf16* __restrict__ xhat,
                                                  const float* __restrict__ g,
                                                  const float* __restrict__ bb,
                                                  bf16* __restrict__ cat) {
  int row = blockIdx.x;
  int bidx = row / 336, n = row - bidx * 336;
  bf16* out = cat + (size_t)row * 1024;
  if (n < 257) {
    const bf16* in = xhat + ((size_t)bidx * 257 + n) * 1024;
#pragma unroll
    for (int j = 0; j < 4; j++) {
      int c = threadIdx.x + j * 256;
      out[c] = __float2bfloat16(__bfloat162float(in[c]) * g[c] + bb[c]);
    }
  } else if (n >= 321) {
#pragma unroll
    for (int j = 0; j < 4; j++)
      out[threadIdx.x + j * 256] = __float2bfloat16(0.f);
  }
}

// ---------------- GEMM: C(MxN) = A(MxK,bf16) @ Bt(NxK,bf16)^T ----------------
// 128x128 tile, BK=32, 4 waves of 64x64, mfma_f32_16x16x32_bf16.

enum { MB_BIAS = 1, MB_RESID = 2, MB_GELU = 4, MB_BF16 = 8 };

template <int MODE>
__global__ void __launch_bounds__(256, 2) gemm_bt(
    const bf16* __restrict__ A, const bf16* __restrict__ Bt,
    void* __restrict__ Cout, const float* __restrict__ bias,
    const float* __restrict__ resid, int M, int N, int K) {
  __shared__ bf16 sA[128 * 32];
  __shared__ bf16 sB[128 * 32];
  int tid = threadIdx.x;
  int wave = tid >> 6, lane = tid & 63;
  int quad = lane >> 4, l16 = lane & 15;
  int wm = (wave >> 1) * 64, wn = (wave & 1) * 64;
  int m0 = blockIdx.y * 128, n0 = blockIdx.x * 128;

  int sRow = tid >> 2;
  int sCol = (tid & 3) * 8;
  const bf16* Ap0 = A + (size_t)min(m0 + sRow, M - 1) * K + sCol;
  const bf16* Ap1 = A + (size_t)min(m0 + 64 + sRow, M - 1) * K + sCol;
  const bf16* Bp0 = Bt + (size_t)(n0 + sRow) * K + sCol;
  const bf16* Bp1 = Bt + (size_t)(n0 + 64 + sRow) * K + sCol;

  f32x4 acc[4][4] = {};

  for (int k0 = 0; k0 < K; k0 += 32) {
    uint4 a0 = *(const uint4*)(Ap0 + k0);
    uint4 a1 = *(const uint4*)(Ap1 + k0);
    uint4 b0 = *(const uint4*)(Bp0 + k0);
    uint4 b1 = *(const uint4*)(Bp1 + k0);
    __syncthreads();
    *(uint4*)&sA[sRow * 32 + sCol] = a0;
    *(uint4*)&sA[(64 + sRow) * 32 + sCol] = a1;
    *(uint4*)&sB[sRow * 32 + sCol] = b0;
    *(uint4*)&sB[(64 + sRow) * 32 + sCol] = b1;
    __syncthreads();
    short8 af[4], bfv[4];
#pragma unroll
    for (int i = 0; i < 4; i++)
      af[i] = *(const short8*)&sA[(wm + i * 16 + l16) * 32 + quad * 8];
#pragma unroll
    for (int j = 0; j < 4; j++)
      bfv[j] = *(const short8*)&sB[(wn + j * 16 + l16) * 32 + quad * 8];
#pragma unroll
    for (int i = 0; i < 4; i++)
#pragma unroll
      for (int j = 0; j < 4; j++)
        acc[i][j] = mfma16(af[i], bfv[j], acc[i][j]);
  }

#pragma unroll
  for (int i = 0; i < 4; i++) {
    int grb = m0 + wm + i * 16 + quad * 4;
#pragma unroll
    for (int j = 0; j < 4; j++) {
      int gc = n0 + wn + j * 16 + l16;
      float bv = (MODE & MB_BIAS) ? bias[gc] : 0.f;
#pragma unroll
      for (int r = 0; r < 4; r++) {
        int gr = grb + r;
        if (gr < M) {
          float vv = acc[i][j][r] + bv;
          if (MODE & MB_GELU) vv = 0.5f * vv * (1.f + erff(vv * 0.70710678118654752f));
          if (MODE & MB_RESID) vv += resid[(size_t)gr * N + gc];
          if (MODE & MB_BF16) ((bf16*)Cout)[(size_t)gr * N + gc] = __float2bfloat16(vv);
          else ((float*)Cout)[(size_t)gr * N + gc] = vv;
        }
      }
    }
  }
}

// ---------------- fused attention: one block per (b,h) ----------------
// q: (b*64+m, h*64+d) bf16;  kv: (b*336+r, [k: h*64+d | v: 1024+h*64+d]) bf16
// valid kv rows: 321 (rows 321..335 are zero pad); scores scaled by 1/8.

__global__ void __launch_bounds__(256, 2) attn(const bf16* __restrict__ qb,
                                               const bf16* __restrict__ kvb,
                                               bf16* __restrict__ ob) {
  __shared__ bf16 sQ[64 * 64];
  __shared__ bf16 sKV[64 * 64];
  __shared__ bf16 sP[64 * 368];   // P in A-layout, cols 0..351 used (336..351 zero)
  __shared__ float sRed[256];

  int h = blockIdx.x, b = blockIdx.y;
  int tid = threadIdx.x, wave = tid >> 6, lane = tid & 63;
  int quad = lane >> 4, l16 = lane & 15;

  const bf16* qg = qb + (size_t)b * 64 * 1024 + h * 64;
  const bf16* kg = kvb + (size_t)b * 336 * 2048 + h * 64;
  const bf16* vg = kg + 1024;

  {
    int r = tid >> 3, c = (tid & 7) * 8;
    *(uint4*)&sQ[r * 64 + c] = *(const uint4*)&qg[(size_t)r * 1024 + c];
    *(uint4*)&sQ[(r + 32) * 64 + c] = *(const uint4*)&qg[(size_t)(r + 32) * 1024 + c];
  }

  f32x4 accS[6][4] = {};   // [kv group of 64][m-tile]; wave owns n-tile g*4+wave

  for (int g = 0; g < 6; g++) {
    __syncthreads();
    {
      int r = tid >> 3, c = (tid & 7) * 8;
      int gr = g * 64 + r;
      if (gr < 336) *(uint4*)&sKV[r * 64 + c] = *(const uint4*)&kg[(size_t)gr * 2048 + c];
      gr += 32;
      if (gr < 336) *(uint4*)&sKV[(r + 32) * 64 + c] = *(const uint4*)&kg[(size_t)gr * 2048 + c];
    }
    __syncthreads();
    if (g * 4 + wave < 21) {
#pragma unroll
      for (int ks = 0; ks < 2; ks++) {
        short8 bfr = *(const short8*)&sKV[(wave * 16 + l16) * 64 + ks * 32 + quad * 8];
#pragma unroll
        for (int i = 0; i < 4; i++) {
          short8 afr = *(const short8*)&sQ[(i * 16 + l16) * 64 + ks * 32 + quad * 8];
          accS[g][i] = mfma16(afr, bfr, accS[g][i]);
        }
      }
    }
  }

  // ---- softmax over 321 valid cols (two-round, running stats in regs) ----
  float rmax[4][4], rsum[4][4];
#pragma unroll
  for (int i = 0; i < 4; i++)
#pragma unroll
    for (int r = 0; r < 4; r++) { rmax[i][r] = -1e30f; rsum[i][r] = 0.f; }

#pragma unroll
  for (int g = 0; g < 6; g++) {
    int col = (g * 4 + wave) * 16 + l16;
    bool valid = col < 321;
#pragma unroll
    for (int i = 0; i < 4; i++)
#pragma unroll
      for (int r = 0; r < 4; r++) {
        float v = accS[g][i][r] * 0.125f;   // (dh^-0.25)^2
        accS[g][i][r] = v;
        if (valid) rmax[i][r] = fmaxf(rmax[i][r], v);
      }
  }
#pragma unroll
  for (int off = 1; off < 16; off <<= 1)
#pragma unroll
    for (int i = 0; i < 4; i++)
#pragma unroll
      for (int r = 0; r < 4; r++)
        rmax[i][r] = fmaxf(rmax[i][r], __shfl_xor(rmax[i][r], off));
  if (l16 == 0) {
#pragma unroll
    for (int i = 0; i < 4; i++)
#pragma unroll
      for (int r = 0; r < 4; r++)
        sRed[wave * 64 + i * 16 + quad * 4 + r] = rmax[i][r];
  }
  __syncthreads();
#pragma unroll
  for (int i = 0; i < 4; i++)
#pragma unroll
    for (int r = 0; r < 4; r++) {
      int row = i * 16 + quad * 4 + r;
      rmax[i][r] = fmaxf(fmaxf(sRed[row], sRed[64 + row]),
                         fmaxf(sRed[128 + row], sRed[192 + row]));
    }
  __syncthreads();   // all reads of maxes done before sRed reuse for sums

#pragma unroll
  for (int g = 0; g < 6; g++) {
    int col = (g * 4 + wave) * 16 + l16;
    bool valid = col < 321;
#pragma unroll
    for (int i = 0; i < 4; i++)
#pragma unroll
      for (int r = 0; r < 4; r++) {
        float pv = valid ? __expf(accS[g][i][r] - rmax[i][r]) : 0.f;
        rsum[i][r] += pv;
        if (col < 352) sP[(i * 16 + quad * 4 + r) * 368 + col] = __float2bfloat16(pv);
      }
  }
#pragma unroll
  for (int off = 1; off < 16; off <<= 1)
#pragma unroll
    for (int i = 0; i < 4; i++)
#pragma unroll
      for (int r = 0; r < 4; r++)
        rsum[i][r] += __shfl_xor(rsum[i][r], off);
  if (l16 == 0) {
#pragma unroll
    for (int i = 0; i < 4; i++)
#pragma unroll
      for (int r = 0; r < 4; r++)
        sRed[wave * 64 + i * 16 + quad * 4 + r] = rsum[i][r];
  }
  __syncthreads();
#pragma unroll
  for (int i = 0; i < 4; i++)
#pragma unroll
    for (int r = 0; r < 4; r++) {
      int row = i * 16 + quad * 4 + r;
      rsum[i][r] = sRed[row] + sRed[64 + row] + sRed[128 + row] + sRed[192 + row];
    }

  // ---- O = P @ V, wave owns dh-tile [wave*16, wave*16+16) ----
  f32x4 accO[4] = {};
  const short* sKVs = (const short*)sKV;
  for (int cch = 0; cch < 6; cch++) {
    __syncthreads();
    {
      int r = tid >> 3, c = (tid & 7) * 8;
      int gr = cch * 64 + r;
      if (gr < 336) *(uint4*)&sKV[r * 64 + c] = *(const uint4*)&vg[(size_t)gr * 2048 + c];
      gr += 32;
      if (gr < 336) *(uint4*)&sKV[(r + 32) * 64 + c] = *(const uint4*)&vg[(size_t)gr * 2048 + c];
    }
    __syncthreads();
    int nks = (cch == 5) ? 1 : 2;   // last chunk: only k=320..352 (P zero past 336)
    for (int ks = 0; ks < nks; ks++) {
      short8 bv;
#pragma unroll
      for (int jj = 0; jj < 8; jj++)
        bv[jj] = sKVs[(ks * 32 + quad * 8 + jj) * 64 + wave * 16 + l16];
#pragma unroll
      for (int i = 0; i < 4; i++) {
        short8 ap = *(const short8*)&sP[(i * 16 + l16) * 368 + cch * 64 + ks * 32 + quad * 8];
        accO[i] = mfma16(ap, bv, accO[i]);
      }
    }
  }

#pragma unroll
  for (int i = 0; i < 4; i++)
#pragma unroll
    for (int r = 0; r < 4; r++) {
      int row = i * 16 + quad * 4 + r;
      ob[(size_t)(b * 64 + row) * 1024 + h * 64 + wave * 16 + l16] =
          __float2bfloat16(accO[i][r] / rsum[i][r]);
    }
}

// ---------------- host orchestration ----------------

extern "C" void kernel_launch(void* const* d_in, const int* in_sizes, int n_in,
                              void* d_out, int out_size, void* d_ws, size_t ws_size,
                              hipStream_t stream) {
  (void)in_sizes; (void)n_in; (void)out_size; (void)ws_size;
  const float* x    = (const float*)d_in[0];
  const float* lin  = (const float*)d_in[1];
  const float* piw  = (const float*)d_in[2];
  const float* pib  = (const float*)d_in[3];
  const float* ln1g = (const float*)d_in[4];
  const float* ln1b = (const float*)d_in[5];
  const float* ln2g = (const float*)d_in[6];
  const float* ln2b = (const float*)d_in[7];
  const float* Wq   = (const float*)d_in[8];
  const float* Wkv  = (const float*)d_in[9];
  const float* Wo   = (const float*)d_in[10];
  const float* ffg  = (const float*)d_in[11];
  const float* ffb  = (const float*)d_in[12];
  const float* W1   = (const float*)d_in[13];
  const float* W2   = (const float*)d_in[14];
  const float* poW  = (const float*)d_in[15];
  const float* pob  = (const float*)d_in[16];
  const float* nog  = (const float*)d_in[17];
  const float* nob  = (const float*)d_in[18];

  char* p = (char*)d_ws;
  auto alloc = [&](size_t bytes) -> char* {
    char* q = p; p += (bytes + 255) & ~(size_t)255; return q;
  };
  // per-layer weight staging (reused each layer) -- keeps ws at ~217 MB
  bf16* pin_t  = (bf16*)alloc((size_t)1024 * 768 * 2);
  bf16* pout_t = (bf16*)alloc((size_t)1024 * 1024 * 2);
  bf16* wq_t   = (bf16*)alloc((size_t)1024 * 1024 * 2);
  bf16* wkv_t  = (bf16*)alloc((size_t)2048 * 1024 * 2);
  bf16* wo_t   = (bf16*)alloc((size_t)1024 * 1024 * 2);
  bf16* w1_t   = (bf16*)alloc((size_t)4096 * 1024 * 2);
  bf16* w2_t   = (bf16*)alloc((size_t)1024 * 4096 * 2);
  bf16* x_bf   = (bf16*)alloc((size_t)8224 * 768 * 2);
  float* xf    = (float*)alloc((size_t)8224 * 1024 * 4);
  bf16* xhat   = (bf16*)alloc((size_t)8224 * 1024 * 2);
  bf16* cat    = (bf16*)alloc((size_t)10752 * 1024 * 2);   // 32 x 336 rows
  bf16* lnlat  = (bf16*)alloc((size_t)2048 * 1024 * 2);
  bf16* qbuf   = (bf16*)alloc((size_t)2048 * 1024 * 2);
  bf16* kvbuf  = (bf16*)alloc((size_t)10752 * 2048 * 2);
  bf16* obuf   = (bf16*)alloc((size_t)2048 * 1024 * 2);
  float* lat   = (float*)alloc((size_t)2048 * 1024 * 4);
  float* lat2  = (float*)alloc((size_t)2048 * 1024 * 4);
  bf16* lnff   = (bf16*)alloc((size_t)2048 * 1024 * 2);
  bf16* h1     = (bf16*)alloc((size_t)2048 * 4096 * 2);
  float* otmp  = (float*)alloc((size_t)2048 * 1024 * 4);

  // prologue
  cvt_f32_bf16<<<6316032 / 256, 256, 0, stream>>>(x, x_bf, 6316032);
  transpose_cvt<<<dim3(32, 24), 256, 0, stream>>>(piw, pin_t, 768, 1024);
  transpose_cvt<<<dim3(32, 32), 256, 0, stream>>>(poW, pout_t, 1024, 1024);
  bcast_latents<<<8192, 256, 0, stream>>>(lin, lat);
  gemm_bt<MB_BIAS><<<dim3(8, 65), 256, 0, stream>>>(x_bf, pin_t, xf, pib, nullptr,
                                                    8224, 1024, 768);
  ln_to_bf16<<<8224, 256, 0, stream>>>(xf, nullptr, nullptr, xhat, nullptr);

  for (int i = 0; i < 8; i++) {
    transpose_cvt<<<dim3(32, 32), 256, 0, stream>>>(Wq + (size_t)i * 1048576, wq_t, 1024, 1024);
    transpose_cvt<<<dim3(64, 32), 256, 0, stream>>>(Wkv + (size_t)i * 2097152, wkv_t, 1024, 2048);
    transpose_cvt<<<dim3(32, 32), 256, 0, stream>>>(Wo + (size_t)i * 1048576, wo_t, 1024, 1024);
    transpose_cvt<<<dim3(128, 32), 256, 0, stream>>>(W1 + (size_t)i * 4194304, w1_t, 1024, 4096);
    transpose_cvt<<<dim3(32, 128), 256, 0, stream>>>(W2 + (size_t)i * 4194304, w2_t, 4096, 1024);

    affine_cat<<<10752, 256, 0, stream>>>(xhat, ln1g + i * 1024, ln1b + i * 1024, cat);
    ln_to_bf16<<<2048, 256, 0, stream>>>(lat, ln2g + i * 1024, ln2b + i * 1024, lnlat, cat);
    gemm_bt<MB_BF16><<<dim3(8, 16), 256, 0, stream>>>(lnlat, wq_t, qbuf, nullptr, nullptr,
                                                      2048, 1024, 1024);
    gemm_bt<MB_BF16><<<dim3(16, 84), 256, 0, stream>>>(cat, wkv_t, kvbuf, nullptr, nullptr,
                                                       10752, 2048, 1024);
    attn<<<dim3(16, 32), 256, 0, stream>>>(qbuf, kvbuf, obuf);
    gemm_bt<MB_RESID><<<dim3(8, 16), 256, 0, stream>>>(obuf, wo_t, lat2, nullptr, lat,
                                                       2048, 1024, 1024);
    ln_to_bf16<<<2048, 256, 0, stream>>>(lat2, ffg + i * 1024, ffb + i * 1024, lnff, nullptr);
    gemm_bt<MB_GELU | MB_BF16><<<dim3(32, 16), 256, 0, stream>>>(lnff, w1_t, h1, nullptr, nullptr,
                                                                 2048, 4096, 1024);
    gemm_bt<MB_RESID><<<dim3(8, 16), 256, 0, stream>>>(h1, w2_t, lat, nullptr, lat2,
                                                       2048, 1024, 4096);
  }

  // epilogue: proj_out + final LN
  cvt_f32_bf16<<<2097152 / 256, 256, 0, stream>>>(lat, lnff, 2097152);
  gemm_bt<MB_BIAS><<<dim3(8, 16), 256, 0, stream>>>(lnff, pout_t, otmp, pob, nullptr,
                                                    2048, 1024, 1024);
  ln_to_f32<<<2048, 256, 0, stream>>>(otmp, nog, nob, (float*)d_out);
}

// Round 2
// 2206.613 us; speedup vs baseline: 1.2919x; 1.2919x over previous
//
#include <hip/hip_runtime.h>
#include <hip/hip_bf16.h>
#include <cstdint>

typedef __hip_bfloat16 bf16;
typedef __attribute__((ext_vector_type(8))) short short8;   // 8 bf16 = 4 VGPRs
typedef __attribute__((ext_vector_type(4))) float f32x4;

__device__ __forceinline__ f32x4 mfma16(short8 a, short8 b, f32x4 c) {
  return __builtin_amdgcn_mfma_f32_16x16x32_bf16(a, b, c, 0, 0, 0);
}

// async global->LDS, 16B per lane; LDS dest = wave-uniform base + lane*16
__device__ __forceinline__ void gload16(const bf16* g, bf16* l) {
  __builtin_amdgcn_global_load_lds((const __attribute__((address_space(1))) void*)g,
                                   (__attribute__((address_space(3))) void*)l, 16, 0, 0);
}

// ---------------- elementwise / conversion ----------------

__global__ void __launch_bounds__(256) cvt_f32_bf16(const float* __restrict__ in,
                                                    bf16* __restrict__ out, int n) {
  int i = blockIdx.x * 256 + threadIdx.x;
  if (i < n) out[i] = __float2bfloat16(in[i]);
}

__global__ void __launch_bounds__(256) bcast_latents(const float* __restrict__ lin,
                                                     float* __restrict__ lat) {
  int i = blockIdx.x * 256 + threadIdx.x;
  lat[i] = lin[i & 65535];   // latents is (64,1024) broadcast over 32 batches
}

// ---------------- transposes: K x N f32 -> N x K bf16 ----------------

__device__ __forceinline__ void trans_tile(float (*tile)[33], const float* __restrict__ src,
                                           bf16* __restrict__ dst, int K, int N,
                                           int bx, int by) {
  int n0 = bx * 32, k0 = by * 32;
  int tx = threadIdx.x & 31, ty = threadIdx.x >> 5;
#pragma unroll
  for (int j = 0; j < 32; j += 8)
    tile[ty + j][tx] = src[(size_t)(k0 + ty + j) * N + n0 + tx];
  __syncthreads();
#pragma unroll
  for (int j = 0; j < 32; j += 8)
    dst[(size_t)(n0 + ty + j) * K + k0 + tx] = __float2bfloat16(tile[tx][ty + j]);
}

__global__ void __launch_bounds__(256) transpose_cvt(const float* __restrict__ src,
                                                     bf16* __restrict__ dst,
                                                     int K, int N) {
  __shared__ float tile[32][33];
  trans_tile(tile, src, dst, K, N, blockIdx.x, blockIdx.y);
}

// all 5 per-layer weights in one launch (12288 blocks of 32x32 tiles)
__global__ void __launch_bounds__(256) transpose_all(
    const float* __restrict__ wq, const float* __restrict__ wkv,
    const float* __restrict__ wo, const float* __restrict__ w1,
    const float* __restrict__ w2, bf16* __restrict__ wq_t, bf16* __restrict__ wkv_t,
    bf16* __restrict__ wo_t, bf16* __restrict__ w1_t, bf16* __restrict__ w2_t) {
  __shared__ float tile[32][33];
  int id = blockIdx.x;
  if (id < 1024) {
    trans_tile(tile, wq, wq_t, 1024, 1024, id & 31, id >> 5);
  } else if (id < 3072) {
    id -= 1024;
    trans_tile(tile, wkv, wkv_t, 1024, 2048, id & 63, id >> 6);
  } else if (id < 4096) {
    id -= 3072;
    trans_tile(tile, wo, wo_t, 1024, 1024, id & 31, id >> 5);
  } else if (id < 8192) {
    id -= 4096;
    trans_tile(tile, w1, w1_t, 1024, 4096, id & 127, id >> 7);
  } else {
    id -= 8192;
    trans_tile(tile, w2, w2_t, 4096, 1024, id & 31, id >> 5);
  }
}

// ---------------- layernorm family (cols fixed at 1024) ----------------

__device__ __forceinline__ void row_stats(const float* x, int tid, float v[4],
                                          float& mean, float& rstd, float* red) {
  float s = 0.f, s2 = 0.f;
#pragma unroll
  for (int j = 0; j < 4; j++) {
    v[j] = x[tid + j * 256];
    s += v[j]; s2 += v[j] * v[j];
  }
#pragma unroll
  for (int o = 32; o > 0; o >>= 1) {
    s += __shfl_down(s, o);
    s2 += __shfl_down(s2, o);
  }
  int w = tid >> 6;
  if ((tid & 63) == 0) { red[w] = s; red[4 + w] = s2; }
  __syncthreads();
  s = red[0] + red[1] + red[2] + red[3];
  s2 = red[4] + red[5] + red[6] + red[7];
  mean = s * (1.f / 1024.f);
  float var = s2 * (1.f / 1024.f) - mean * mean;
  rstd = rsqrtf(var + 1e-5f);
}

__global__ void __launch_bounds__(256) ln_to_bf16(const float* __restrict__ in,
                                                  const float* __restrict__ g,
                                                  const float* __restrict__ bb,
                                                  bf16* __restrict__ out) {
  __shared__ float red[8];
  int row = blockIdx.x, tid = threadIdx.x;
  const float* x = in + (size_t)row * 1024;
  float v[4], mean, rstd;
  row_stats(x, tid, v, mean, rstd, red);
  bf16* o1 = out + (size_t)row * 1024;
#pragma unroll
  for (int j = 0; j < 4; j++) {
    int c = tid + j * 256;
    float y = (v[j] - mean) * rstd;
    if (g) y = y * g[c] + bb[c];
    o1[c] = __float2bfloat16(y);
  }
}

__global__ void __launch_bounds__(256) ln_to_f32(const float* __restrict__ in,
                                                 const float* __restrict__ g,
                                                 const float* __restrict__ bb,
                                                 float* __restrict__ out) {
  __shared__ float red[8];
  int row = blockIdx.x, tid = threadIdx.x;
  const float* x = in + (size_t)row * 1024;
  float v[4], mean, rstd;
  row_stats(x, tid, v, mean, rstd, red);
  float* o1 = out + (size_t)row * 1024;
#pragma unroll
  for (int j = 0; j < 4; j++) {
    int c = tid + j * 256;
    o1[c] = (v[j] - mean) * rstd * g[c] + bb[c];
  }
}

// cat rows per batch (336) = [xn affine(257) | LN(lat)(64) | zero pad(15)].
// Also writes lnlat (the LN'd latents) for the q GEMM.
__global__ void __launch_bounds__(256) lncat(const bf16* __restrict__ xhat,
                                             const float* __restrict__ lat,
                                             const float* __restrict__ g1,
                                             const float* __restrict__ b1,
                                             const float* __restrict__ g2,
                                             const float* __restrict__ b2,
                                             bf16* __restrict__ cat,
                                             bf16* __restrict__ lnlat) {
  __shared__ float red[8];
  int row = blockIdx.x, tid = threadIdx.x;
  int bidx = row / 336, n = row - bidx * 336;
  bf16* out = cat + (size_t)row * 1024;
  if (n < 257) {
    const bf16* in = xhat + ((size_t)bidx * 257 + n) * 1024;
#pragma unroll
    for (int j = 0; j < 4; j++) {
      int c = tid + j * 256;
      out[c] = __float2bfloat16(__bfloat162float(in[c]) * g1[c] + b1[c]);
    }
  } else if (n < 321) {
    int lrow = bidx * 64 + (n - 257);
    const float* x = lat + (size_t)lrow * 1024;
    float v[4], mean, rstd;
    row_stats(x, tid, v, mean, rstd, red);
    bf16* o2 = lnlat + (size_t)lrow * 1024;
#pragma unroll
    for (int j = 0; j < 4; j++) {
      int c = tid + j * 256;
      bf16 hh = __float2bfloat16((v[j] - mean) * rstd * g2[c] + b2[c]);
      out[c] = hh;
      o2[c] = hh;
    }
  } else {
#pragma unroll
    for (int j = 0; j < 4; j++)
      out[tid + j * 256] = __float2bfloat16(0.f);
  }
}

// ---------------- GEMM: C(MxN) = A(MxK,bf16) @ Bt(NxK,bf16)^T ----------------
// 128x128 tile, BK=32, 4 waves of 64x64, mfma_f32_16x16x32_bf16.
// Staging via global_load_lds width=16 (m97 2-barrier structure).
// grid.z = split-K factor S; MODE=0 writes f32 partials at z*M*N.

enum { MB_BIAS = 1, MB_RESID = 2, MB_GELU = 4, MB_BF16 = 8 };

template <int MODE>
__global__ void __launch_bounds__(256, 2) gemm_bt(
    const bf16* __restrict__ A, const bf16* __restrict__ Bt,
    void* __restrict__ Cout, const float* __restrict__ bias,
    const float* __restrict__ resid, int M, int N, int K) {
  __shared__ bf16 sA[128 * 32];
  __shared__ bf16 sB[128 * 32];
  int tid = threadIdx.x;
  int wave = tid >> 6, lane = tid & 63;
  int quad = lane >> 4, l16 = lane & 15;
  int wm = (wave >> 1) * 64, wn = (wave & 1) * 64;
  int m0 = blockIdx.y * 128, n0 = blockIdx.x * 128;
  int z = blockIdx.z;
  int kPer = K / gridDim.z;
  int kBeg = z * kPer, kEnd = kBeg + kPer;

  // staging map: wave w, lane l -> row w*16 + (l>>2), col (l&3)*8  (+64 rows, 2nd issue)
  int srow = wave * 16 + (lane >> 2);
  int scol = (lane & 3) * 8;
  const bf16* gA0 = A + (size_t)min(m0 + srow, M - 1) * K + scol;
  const bf16* gA1 = A + (size_t)min(m0 + 64 + srow, M - 1) * K + scol;
  const bf16* gB0 = Bt + (size_t)(n0 + srow) * K + scol;
  const bf16* gB1 = Bt + (size_t)(n0 + 64 + srow) * K + scol;
  bf16* lA0 = &sA[(wave * 16) * 32];
  bf16* lA1 = &sA[(64 + wave * 16) * 32];
  bf16* lB0 = &sB[(wave * 16) * 32];
  bf16* lB1 = &sB[(64 + wave * 16) * 32];

  f32x4 acc[4][4] = {};

  for (int k0 = kBeg; k0 < kEnd; k0 += 32) {
    gload16(gA0 + k0, lA0);
    gload16(gA1 + k0, lA1);
    gload16(gB0 + k0, lB0);
    gload16(gB1 + k0, lB1);
    __syncthreads();   // drains vmcnt: staged data visible
    short8 af[4], bfv[4];
#pragma unroll
    for (int i = 0; i < 4; i++)
      af[i] = *(const short8*)&sA[(wm + i * 16 + l16) * 32 + quad * 8];
#pragma unroll
    for (int j = 0; j < 4; j++)
      bfv[j] = *(const short8*)&sB[(wn + j * 16 + l16) * 32 + quad * 8];
#pragma unroll
    for (int i = 0; i < 4; i++)
#pragma unroll
      for (int j = 0; j < 4; j++)
        acc[i][j] = mfma16(af[i], bfv[j], acc[i][j]);
    __syncthreads();   // all frag reads done before next iteration's stores
  }

  float* cf = (float*)Cout + (size_t)z * ((size_t)M * N);
#pragma unroll
  for (int i = 0; i < 4; i++) {
    int grb = m0 + wm + i * 16 + quad * 4;
#pragma unroll
    for (int j = 0; j < 4; j++) {
      int gc = n0 + wn + j * 16 + l16;
      float bv = (MODE & MB_BIAS) ? bias[gc] : 0.f;
#pragma unroll
      for (int r = 0; r < 4; r++) {
        int gr = grb + r;
        if (gr < M) {
          float vv = acc[i][j][r] + bv;
          if (MODE & MB_GELU) vv = 0.5f * vv * (1.f + erff(vv * 0.70710678118654752f));
          if (MODE & MB_RESID) vv += resid[(size_t)gr * N + gc];
          if (MODE & MB_BF16) ((bf16*)Cout)[(size_t)gr * N + gc] = __float2bfloat16(vv);
          else cf[(size_t)gr * N + gc] = vv;
        }
      }
    }
  }
}

// ---------------- split-K reduce (+bias/resid, f32 or bf16 out) ----------------

enum { RD_BIAS = 1, RD_RESID = 2, RD_BF16 = 4 };

template <int MODE>
__global__ void __launch_bounds__(256) reduce_k(const float* __restrict__ parts, int S,
                                                int MN, int N,
                                                const float* __restrict__ bias,
                                                const float* __restrict__ resid,
                                                void* __restrict__ out) {
  int i4 = (blockIdx.x * 256 + threadIdx.x) * 4;
  if (i4 >= MN) return;
  float4 a = *(const float4*)&parts[i4];
#pragma unroll 4
  for (int s = 1; s < S; s++) {
    float4 b = *(const float4*)&parts[(size_t)s * MN + i4];
    a.x += b.x; a.y += b.y; a.z += b.z; a.w += b.w;
  }
  if (MODE & RD_BIAS) {
    float4 b = *(const float4*)&bias[i4 & (N - 1)];
    a.x += b.x; a.y += b.y; a.z += b.z; a.w += b.w;
  }
  if (MODE & RD_RESID) {
    float4 b = *(const float4*)&resid[i4];
    a.x += b.x; a.y += b.y; a.z += b.z; a.w += b.w;
  }
  if (MODE & RD_BF16) {
    bf16 o[4] = {__float2bfloat16(a.x), __float2bfloat16(a.y),
                 __float2bfloat16(a.z), __float2bfloat16(a.w)};
    *(uint2*)&((bf16*)out)[i4] = *(uint2*)o;
  } else {
    *(float4*)&((float*)out)[i4] = a;
  }
}

// ---------------- fused attention: one block per (b,h) ----------------
// q: (b*64+m, h*64+d) bf16;  kv: (b*336+r, [k: h*64+d | v: 1024+h*64+d]) bf16
// valid kv rows: 321 (rows 321..335 are zero pad); scores scaled by 1/8.

__global__ void __launch_bounds__(256, 2) attn(const bf16* __restrict__ qb,
                                               const bf16* __restrict__ kvb,
                                               bf16* __restrict__ ob) {
  __shared__ bf16 sQ[64 * 64];
  __shared__ bf16 sKV[64 * 64];
  __shared__ bf16 sP[64 * 368];   // P in A-layout, cols 0..351 used (336..351 zero)
  __shared__ float sRed[256];

  int h = blockIdx.x, b = blockIdx.y;
  int tid = threadIdx.x, wave = tid >> 6, lane = tid & 63;
  int quad = lane >> 4, l16 = lane & 15;

  const bf16* qg = qb + (size_t)b * 64 * 1024 + h * 64;
  const bf16* kg = kvb + (size_t)b * 336 * 2048 + h * 64;
  const bf16* vg = kg + 1024;

  {
    int r = tid >> 3, c = (tid & 7) * 8;
    *(uint4*)&sQ[r * 64 + c] = *(const uint4*)&qg[(size_t)r * 1024 + c];
    *(uint4*)&sQ[(r + 32) * 64 + c] = *(const uint4*)&qg[(size_t)(r + 32) * 1024 + c];
  }

  f32x4 accS[6][4] = {};   // [kv group of 64][m-tile]; wave owns n-tile g*4+wave

  for (int g = 0; g < 6; g++) {
    __syncthreads();
    {
      int r = tid >> 3, c = (tid & 7) * 8;
      int gr = g * 64 + r;
      if (gr < 336) *(uint4*)&sKV[r * 64 + c] = *(const uint4*)&kg[(size_t)gr * 2048 + c];
      gr += 32;
      if (gr < 336) *(uint4*)&sKV[(r + 32) * 64 + c] = *(const uint4*)&kg[(size_t)gr * 2048 + c];
    }
    __syncthreads();
    if (g * 4 + wave < 21) {
#pragma unroll
      for (int ks = 0; ks < 2; ks++) {
        short8 bfr = *(const short8*)&sKV[(wave * 16 + l16) * 64 + ks * 32 + quad * 8];
#pragma unroll
        for (int i = 0; i < 4; i++) {
          short8 afr = *(const short8*)&sQ[(i * 16 + l16) * 64 + ks * 32 + quad * 8];
          accS[g][i] = mfma16(afr, bfr, accS[g][i]);
        }
      }
    }
  }

  // ---- softmax over 321 valid cols ----
  float rmax[4][4], rsum[4][4];
#pragma unroll
  for (int i = 0; i < 4; i++)
#pragma unroll
    for (int r = 0; r < 4; r++) { rmax[i][r] = -1e30f; rsum[i][r] = 0.f; }

#pragma unroll
  for (int g = 0; g < 6; g++) {
    int col = (g * 4 + wave) * 16 + l16;
    bool valid = col < 321;
#pragma unroll
    for (int i = 0; i < 4; i++)
#pragma unroll
      for (int r = 0; r < 4; r++) {
        float v = accS[g][i][r] * 0.125f;   // (dh^-0.25)^2
        accS[g][i][r] = v;
        if (valid) rmax[i][r] = fmaxf(rmax[i][r], v);
      }
  }
#pragma unroll
  for (int off = 1; off < 16; off <<= 1)
#pragma unroll
    for (int i = 0; i < 4; i++)
#pragma unroll
      for (int r = 0; r < 4; r++)
        rmax[i][r] = fmaxf(rmax[i][r], __shfl_xor(rmax[i][r], off));
  if (l16 == 0) {
#pragma unroll
    for (int i = 0; i < 4; i++)
#pragma unroll
      for (int r = 0; r < 4; r++)
        sRed[wave * 64 + i * 16 + quad * 4 + r] = rmax[i][r];
  }
  __syncthreads();
#pragma unroll
  for (int i = 0; i < 4; i++)
#pragma unroll
    for (int r = 0; r < 4; r++) {
      int row = i * 16 + quad * 4 + r;
      rmax[i][r] = fmaxf(fmaxf(sRed[row], sRed[64 + row]),
                         fmaxf(sRed[128 + row], sRed[192 + row]));
    }
  __syncthreads();

#pragma unroll
  for (int g = 0; g < 6; g++) {
    int col = (g * 4 + wave) * 16 + l16;
    bool valid = col < 321;
#pragma unroll
    for (int i = 0; i < 4; i++)
#pragma unroll
      for (int r = 0; r < 4; r++) {
        float pv = valid ? __expf(accS[g][i][r] - rmax[i][r]) : 0.f;
        rsum[i][r] += pv;
        if (col < 352) sP[(i * 16 + quad * 4 + r) * 368 + col] = __float2bfloat16(pv);
      }
  }
#pragma unroll
  for (int off = 1; off < 16; off <<= 1)
#pragma unroll
    for (int i = 0; i < 4; i++)
#pragma unroll
      for (int r = 0; r < 4; r++)
        rsum[i][r] += __shfl_xor(rsum[i][r], off);
  if (l16 == 0) {
#pragma unroll
    for (int i = 0; i < 4; i++)
#pragma unroll
      for (int r = 0; r < 4; r++)
        sRed[wave * 64 + i * 16 + quad * 4 + r] = rsum[i][r];
  }
  __syncthreads();
#pragma unroll
  for (int i = 0; i < 4; i++)
#pragma unroll
    for (int r = 0; r < 4; r++) {
      int row = i * 16 + quad * 4 + r;
      rsum[i][r] = sRed[row] + sRed[64 + row] + sRed[128 + row] + sRed[192 + row];
    }

  // ---- O = P @ V, wave owns dh-tile [wave*16, wave*16+16) ----
  f32x4 accO[4] = {};
  const short* sKVs = (const short*)sKV;
  for (int cch = 0; cch < 6; cch++) {
    __syncthreads();
    {
      int r = tid >> 3, c = (tid & 7) * 8;
      int gr = cch * 64 + r;
      if (gr < 336) *(uint4*)&sKV[r * 64 + c] = *(const uint4*)&vg[(size_t)gr * 2048 + c];
      gr += 32;
      if (gr < 336) *(uint4*)&sKV[(r + 32) * 64 + c] = *(const uint4*)&vg[(size_t)gr * 2048 + c];
    }
    __syncthreads();
    int nks = (cch == 5) ? 1 : 2;   // last chunk: P zero past col 336
    for (int ks = 0; ks < nks; ks++) {
      short8 bv;
#pragma unroll
      for (int jj = 0; jj < 8; jj++)
        bv[jj] = sKVs[(ks * 32 + quad * 8 + jj) * 64 + wave * 16 + l16];
#pragma unroll
      for (int i = 0; i < 4; i++) {
        short8 ap = *(const short8*)&sP[(i * 16 + l16) * 368 + cch * 64 + ks * 32 + quad * 8];
        accO[i] = mfma16(ap, bv, accO[i]);
      }
    }
  }

#pragma unroll
  for (int i = 0; i < 4; i++)
#pragma unroll
    for (int r = 0; r < 4; r++) {
      int row = i * 16 + quad * 4 + r;
      ob[(size_t)(b * 64 + row) * 1024 + h * 64 + wave * 16 + l16] =
          __float2bfloat16(accO[i][r] / rsum[i][r]);
    }
}

// ---------------- host orchestration ----------------

extern "C" void kernel_launch(void* const* d_in, const int* in_sizes, int n_in,
                              void* d_out, int out_size, void* d_ws, size_t ws_size,
                              hipStream_t stream) {
  (void)in_sizes; (void)n_in; (void)out_size; (void)ws_size;
  const float* x    = (const float*)d_in[0];
  const float* lin  = (const float*)d_in[1];
  const float* piw  = (const float*)d_in[2];
  const float* pib  = (const float*)d_in[3];
  const float* ln1g = (const float*)d_in[4];
  const float* ln1b = (const float*)d_in[5];
  const float* ln2g = (const float*)d_in[6];
  const float* ln2b = (const float*)d_in[7];
  const float* Wq   = (const float*)d_in[8];
  const float* Wkv  = (const float*)d_in[9];
  const float* Wo   = (const float*)d_in[10];
  const float* ffg  = (const float*)d_in[11];
  const float* ffb  = (const float*)d_in[12];
  const float* W1   = (const float*)d_in[13];
  const float* W2   = (const float*)d_in[14];
  const float* poW  = (const float*)d_in[15];
  const float* pob  = (const float*)d_in[16];
  const float* nog  = (const float*)d_in[17];
  const float* nob  = (const float*)d_in[18];

  char* p = (char*)d_ws;
  auto alloc = [&](size_t bytes) -> char* {
    char* q = p; p += (bytes + 255) & ~(size_t)255; return q;
  };
  bf16* pin_t  = (bf16*)alloc((size_t)1024 * 768 * 2);
  bf16* pout_t = (bf16*)alloc((size_t)1024 * 1024 * 2);
  bf16* wq_t   = (bf16*)alloc((size_t)1024 * 1024 * 2);
  bf16* wkv_t  = (bf16*)alloc((size_t)2048 * 1024 * 2);
  bf16* wo_t   = (bf16*)alloc((size_t)1024 * 1024 * 2);
  bf16* w1_t   = (bf16*)alloc((size_t)4096 * 1024 * 2);
  bf16* w2_t   = (bf16*)alloc((size_t)1024 * 4096 * 2);
  bf16* x_bf   = (bf16*)alloc((size_t)8224 * 768 * 2);
  float* xf    = (float*)alloc((size_t)8224 * 1024 * 4);   // prologue xf; later: split-K partials
  bf16* xhat   = (bf16*)alloc((size_t)8224 * 1024 * 2);
  bf16* cat    = (bf16*)alloc((size_t)10752 * 1024 * 2);   // 32 x 336 rows
  bf16* lnlat  = (bf16*)alloc((size_t)2048 * 1024 * 2);
  bf16* qbuf   = (bf16*)alloc((size_t)2048 * 1024 * 2);
  bf16* kvbuf  = (bf16*)alloc((size_t)10752 * 2048 * 2);
  bf16* obuf   = (bf16*)alloc((size_t)2048 * 1024 * 2);
  float* lat   = (float*)alloc((size_t)2048 * 1024 * 4);
  float* lat2  = (float*)alloc((size_t)2048 * 1024 * 4);
  bf16* lnff   = (bf16*)alloc((size_t)2048 * 1024 * 2);
  bf16* h1     = (bf16*)alloc((size_t)2048 * 4096 * 2);
  float* otmp  = (float*)alloc((size_t)2048 * 1024 * 4);

  const int MN = 2048 * 1024;   // split-K partial plane size

  // prologue
  cvt_f32_bf16<<<6316032 / 256, 256, 0, stream>>>(x, x_bf, 6316032);
  transpose_cvt<<<dim3(32, 24), 256, 0, stream>>>(piw, pin_t, 768, 1024);
  transpose_cvt<<<dim3(32, 32), 256, 0, stream>>>(poW, pout_t, 1024, 1024);
  bcast_latents<<<8192, 256, 0, stream>>>(lin, lat);
  gemm_bt<MB_BIAS><<<dim3(8, 65), 256, 0, stream>>>(x_bf, pin_t, xf, pib, nullptr,
                                                    8224, 1024, 768);
  ln_to_bf16<<<8224, 256, 0, stream>>>(xf, nullptr, nullptr, xhat);

  for (int i = 0; i < 8; i++) {
    transpose_all<<<12288, 256, 0, stream>>>(
        Wq + (size_t)i * 1048576, Wkv + (size_t)i * 2097152, Wo + (size_t)i * 1048576,
        W1 + (size_t)i * 4194304, W2 + (size_t)i * 4194304,
        wq_t, wkv_t, wo_t, w1_t, w2_t);
    lncat<<<10752, 256, 0, stream>>>(xhat, lat, ln1g + i * 1024, ln1b + i * 1024,
                                     ln2g + i * 1024, ln2b + i * 1024, cat, lnlat);
    // q = lnlat @ Wq  (split-K=4 -> 512 blocks)
    gemm_bt<0><<<dim3(8, 16, 4), 256, 0, stream>>>(lnlat, wq_t, xf, nullptr, nullptr,
                                                   2048, 1024, 1024);
    reduce_k<RD_BF16><<<MN / 1024, 256, 0, stream>>>(xf, 4, MN, 1024, nullptr, nullptr, qbuf);
    // kv = cat @ Wkv
    gemm_bt<MB_BF16><<<dim3(16, 84), 256, 0, stream>>>(cat, wkv_t, kvbuf, nullptr, nullptr,
                                                       10752, 2048, 1024);
    attn<<<dim3(16, 32), 256, 0, stream>>>(qbuf, kvbuf, obuf);
    // lat2 = o @ Wo + lat  (split-K=4)
    gemm_bt<0><<<dim3(8, 16, 4), 256, 0, stream>>>(obuf, wo_t, xf, nullptr, nullptr,
                                                   2048, 1024, 1024);
    reduce_k<RD_RESID><<<MN / 1024, 256, 0, stream>>>(xf, 4, MN, 1024, nullptr, lat, lat2);
    ln_to_bf16<<<2048, 256, 0, stream>>>(lat2, ffg + i * 1024, ffb + i * 1024, lnff);
    gemm_bt<MB_GELU | MB_BF16><<<dim3(32, 16), 256, 0, stream>>>(lnff, w1_t, h1, nullptr,
                                                                 nullptr, 2048, 4096, 1024);
    // lat = h1 @ W2 + lat2  (split-K=4, Kper=1024)
    gemm_bt<0><<<dim3(8, 16, 4), 256, 0, stream>>>(h1, w2_t, xf, nullptr, nullptr,
                                                   2048, 1024, 4096);
    reduce_k<RD_RESID><<<MN / 1024, 256, 0, stream>>>(xf, 4, MN, 1024, nullptr, lat2, lat);
  }

  // epilogue: proj_out + final LN
  cvt_f32_bf16<<<2097152 / 256, 256, 0, stream>>>(lat, lnff, 2097152);
  gemm_bt<0><<<dim3(8, 16, 4), 256, 0, stream>>>(lnff, pout_t, xf, nullptr, nullptr,
                                                 2048, 1024, 1024);
  reduce_k<RD_BIAS><<<MN / 1024, 256, 0, stream>>>(xf, 4, MN, 1024, pob, nullptr, otmp);
  ln_to_f32<<<2048, 256, 0, stream>>>(otmp, nog, nob, (float*)d_out);
}